// Round 4
// baseline (225.323 us; speedup 1.0000x reference)
//
#include <hip/hip_runtime.h>
#include <hip/hip_bf16.h>

// out[b, s, d] = in[b, s, d] + pe[s, d]
// pe[s, 2p]   = sin(s / 10000^(2p/1024)),  pe[s, 2p+1] = cos(...)
//
// R3 post-mortem: single fused kernel pays 2 exp2f + 2 sincosf (TRANS pipe,
// quarter rate, ~40+ instrs) per 32 B of traffic -> ~75 us, trig-throttled.
// Fix per App-B: precompute the 16 MiB PE table (S x D fp32) into d_ws
// (kernel 1, 1/8 the trig work, off the critical path), then the hot kernel
// is a pure streaming add:
//   - input:  nontemporal load  (read-once, don't pollute L2/L3)
//   - pe:     cached load       (read 8x, L3-resident after first touch)
//   - output: nontemporal store (write-once)
// Compulsory HBM traffic ~272 MiB -> ~43 us at the measured 6.5-6.7 TB/s.

#define SEQ_LEN 4096
#define D_MODEL 1024

using f32x4 = __attribute__((ext_vector_type(4))) float;

__global__ void __launch_bounds__(256)
pe_table_kernel(float* __restrict__ pe) {
    constexpr int D4 = D_MODEL / 4;                    // 256 float4s per row
    int idx = blockIdx.x * blockDim.x + threadIdx.x;   // 0 .. SEQ_LEN*D4-1
    int d4  = idx & (D4 - 1);
    int s   = idx >> 8;

    // angle(p) = s * 10000^(-2p/1024) = s * exp2(-p * (2/1024)*log2(10000))
    constexpr float K = -0.025952563241307517f;
    float sf   = (float)s;
    int   p0   = d4 * 2;
    float ang0 = sf * exp2f((float)p0 * K);
    float ang1 = sf * exp2f((float)(p0 + 1) * K);
    float s0, c0, s1, c1;
    sincosf(ang0, &s0, &c0);
    sincosf(ang1, &s1, &c1);

    reinterpret_cast<f32x4*>(pe)[idx] = f32x4{s0, c0, s1, c1};
}

__global__ void __launch_bounds__(256)
pe_add_kernel(const float* __restrict__ in, const float* __restrict__ pe,
              float* __restrict__ out) {
    constexpr int PLANE4 = SEQ_LEN * (D_MODEL / 4);    // 1M float4s per image

    int idx = blockIdx.x * blockDim.x + threadIdx.x;   // 0 .. 8*PLANE4-1

    f32x4 v = __builtin_nontemporal_load(
                  reinterpret_cast<const f32x4*>(in) + idx);
    f32x4 p = reinterpret_cast<const f32x4*>(pe)[idx & (PLANE4 - 1)];

    v.x += p.x; v.y += p.y; v.z += p.z; v.w += p.w;
    __builtin_nontemporal_store(v, reinterpret_cast<f32x4*>(out) + idx);
}

// Fallback if ws is too small (shouldn't happen: observed ws = 512 MiB).
__global__ void __launch_bounds__(256)
pe_add_fused_kernel(const float* __restrict__ in, float* __restrict__ out) {
    constexpr int D4 = D_MODEL / 4;
    int idx = blockIdx.x * blockDim.x + threadIdx.x;
    f32x4 v = *(reinterpret_cast<const f32x4*>(in) + idx);
    int d4 = idx & (D4 - 1);
    int s  = (idx >> 8) & (SEQ_LEN - 1);
    constexpr float K = -0.025952563241307517f;
    float sf = (float)s;
    int p0 = d4 * 2;
    float ang0 = sf * exp2f((float)p0 * K);
    float ang1 = sf * exp2f((float)(p0 + 1) * K);
    float s0, c0, s1, c1;
    sincosf(ang0, &s0, &c0);
    sincosf(ang1, &s1, &c1);
    v.x += s0; v.y += c0; v.z += s1; v.w += c1;
    __builtin_nontemporal_store(v, reinterpret_cast<f32x4*>(out) + idx);
}

extern "C" void kernel_launch(void* const* d_in, const int* in_sizes, int n_in,
                              void* d_out, int out_size, void* d_ws, size_t ws_size,
                              hipStream_t stream) {
    const float* in  = (const float*)d_in[0];
    float*       out = (float*)d_out;

    constexpr size_t PE_BYTES = (size_t)SEQ_LEN * D_MODEL * sizeof(float);
    int total4 = in_sizes[0] / 4;                      // 8,388,608 float4s

    if (ws_size >= PE_BYTES) {
        float* pe = (float*)d_ws;
        constexpr int T1 = SEQ_LEN * (D_MODEL / 4);    // 1,048,576
        pe_table_kernel<<<T1 / 256, 256, 0, stream>>>(pe);
        pe_add_kernel<<<total4 / 256, 256, 0, stream>>>(in, pe, out);
    } else {
        pe_add_fused_kernel<<<total4 / 256, 256, 0, stream>>>(in, out);
    }
}